// Round 1
// baseline (275.465 us; speedup 1.0000x reference)
//
#include <hip/hip_runtime.h>
#include <math.h>

#define H 128
#define L 8192
#define NSTATE 64
#define NTH 1024
#define LPT (L / NTH) /* 8 l-values per thread */
#define PI_D 3.14159265358979323846

__device__ __forceinline__ float2 cmulf(float2 a, float2 b) {
    return make_float2(a.x * b.x - a.y * b.y, a.x * b.y + a.y * b.x);
}

// In-place radix-2 DIT FFT of 8192 complex floats in LDS.
// tw holds e^{-2*pi*i*j/8192} for j=0..2047 (extended by symmetry: idx>=2048 -> *(-i)).
// Caller must be __syncthreads()-clean before calling; returns synced.
__device__ void fft8192(float2* __restrict__ buf, const float2* __restrict__ tw,
                        int tid, bool inverse) {
    // bit-reversal permutation (13 bits)
    for (int i = tid; i < L; i += NTH) {
        int j = (int)(__brev((unsigned)i) >> 19);
        if (j > i) { float2 a = buf[i]; buf[i] = buf[j]; buf[j] = a; }
    }
    __syncthreads();
    for (int s = 1; s <= 13; ++s) {
        int half = 1 << (s - 1);
        for (int b = tid; b < (L >> 1); b += NTH) {
            int j = b & (half - 1);
            int i0 = ((b >> (s - 1)) << s) + j;
            int i1 = i0 + half;
            int idx = j << (13 - s);           // j * (8192/len), in [0,4096)
            float2 w;
            if (idx < 2048) w = tw[idx];
            else { float2 t = tw[idx - 2048]; w = make_float2(t.y, -t.x); } // * e^{-i pi/2}
            if (inverse) w.y = -w.y;
            float2 x0 = buf[i0], x1 = buf[i1];
            float2 t1 = cmulf(w, x1);
            buf[i0] = make_float2(x0.x + t1.x, x0.y + t1.y);
            buf[i1] = make_float2(x0.x - t1.x, x0.y - t1.y);
        }
        __syncthreads();
    }
}

extern __shared__ char smem_raw[];

__global__ __launch_bounds__(NTH)
void s4_fused_kernel(const float* __restrict__ u,
                     const float* __restrict__ Ct_ri,
                     const float* __restrict__ B_raw,
                     const float* __restrict__ Dp,
                     const float* __restrict__ log_step,
                     const float* __restrict__ Lre_g,
                     const float* __restrict__ Lim_g,
                     const float* __restrict__ p_re,
                     const float* __restrict__ p_im,
                     const float* __restrict__ q_re,
                     const float* __restrict__ q_im,
                     const float* __restrict__ Vc_re,
                     const float* __restrict__ Vc_im,
                     float* __restrict__ out)
{
    float2* bufA = (float2*)smem_raw;          // 8192 complex
    float2* bufB = bufA + L;                   // 8192 complex
    float2* tw   = bufB + L;                   // 2048 complex twiddles
    float2* w00  = tw + 2048;                  // 64
    float2* w01  = w00 + NSTATE;               // 64
    float2* w10  = w01 + NSTATE;               // 64
    float2* w11  = w10 + NSTATE;               // 64
    float*  lre  = (float*)(w11 + NSTATE);     // 64
    float*  lim  = lre + NSTATE;               // 64

    const int h   = blockIdx.x;
    const int tid = threadIdx.x;

    // ---- setup: twiddle table (double-precision angles) ----
    for (int j = tid; j < 2048; j += NTH) {
        double a = -2.0 * PI_D * (double)j / (double)L;
        tw[j] = make_float2((float)cos(a), (float)sin(a));
    }
    // ---- setup: per-channel Cauchy weights ----
    if (tid < NSTATE) {
        int n = tid;
        float2 Bc = make_float2(0.f, 0.f);
        for (int m = 0; m < NSTATE; ++m) {
            float br = B_raw[h * NSTATE + m];
            Bc.x += Vc_re[n * NSTATE + m] * br;
            Bc.y += Vc_im[n * NSTATE + m] * br;
        }
        float2 Ctc = make_float2(Ct_ri[(h * NSTATE + n) * 2 + 0],
                                 -Ct_ri[(h * NSTATE + n) * 2 + 1]);
        float2 pc = make_float2(p_re[n], p_im[n]);
        float2 qc = make_float2(q_re[n], -q_im[n]);
        w00[n] = cmulf(Ctc, Bc);
        w01[n] = cmulf(Ctc, pc);
        w10[n] = cmulf(qc, Bc);
        w11[n] = cmulf(qc, pc);
        lre[n] = Lre_g[n];
        lim[n] = Lim_g[n];
    }
    __syncthreads();

    const float step = expf(log_step[h]);
    const float two_over_step = 2.0f / step;
    const float Dh = Dp[h];

    // ---- phase 1: at_roots[l] = c * (k00 - k01*k10/(1+k11)) ----
    // g = i*(2/step)*tan(pi*l/L)  (purely imaginary); c = 1 + i*tan(pi*l/L)
    float tl[LPT], gim[LPT];
    float2 a00[LPT], a01[LPT], a10[LPT], a11[LPT];
    #pragma unroll
    for (int il = 0; il < LPT; ++il) {
        int l = tid + il * NTH;
        double th = PI_D * (double)l / (double)L;
        float t = (float)tan(th);
        t = fminf(fmaxf(t, -3.0e7f), 3.0e7f);   // only l=L/2 clamps; c/g cancels there
        tl[il] = t;
        gim[il] = two_over_step * t;
        a00[il] = make_float2(0.f, 0.f);
        a01[il] = make_float2(0.f, 0.f);
        a10[il] = make_float2(0.f, 0.f);
        a11[il] = make_float2(0.f, 0.f);
    }
    for (int n = 0; n < NSTATE; ++n) {
        float2 c00 = w00[n], c01 = w01[n], c10 = w10[n], c11 = w11[n];
        float dre = -lre[n];
        float li  = lim[n];
        #pragma unroll
        for (int il = 0; il < LPT; ++il) {
            float dim = gim[il] - li;
            float den = dre * dre + dim * dim;
            float inv = 1.0f / den;
            float rre = dre * inv;
            float rim = -dim * inv;
            a00[il].x += c00.x * rre - c00.y * rim; a00[il].y += c00.x * rim + c00.y * rre;
            a01[il].x += c01.x * rre - c01.y * rim; a01[il].y += c01.x * rim + c01.y * rre;
            a10[il].x += c10.x * rre - c10.y * rim; a10[il].y += c10.x * rim + c10.y * rre;
            a11[il].x += c11.x * rre - c11.y * rim; a11[il].y += c11.x * rim + c11.y * rre;
        }
    }
    #pragma unroll
    for (int il = 0; il < LPT; ++il) {
        int l = tid + il * NTH;
        float2 den1 = make_float2(1.0f + a11[il].x, a11[il].y);
        float inv = 1.0f / (den1.x * den1.x + den1.y * den1.y);
        float2 qn = cmulf(a01[il], a10[il]);
        float2 dv = make_float2((qn.x * den1.x + qn.y * den1.y) * inv,
                                (qn.y * den1.x - qn.x * den1.y) * inv);
        float2 tmp = make_float2(a00[il].x - dv.x, a00[il].y - dv.y);
        float2 c = make_float2(1.0f, tl[il]);
        bufA[l] = cmulf(c, tmp);
    }
    __syncthreads();

    // ---- phase 2: K = Re(IFFT_L(at_roots)) ----
    fft8192(bufA, tw, tid, true);

    // ---- phase 3: pack K (with 1/L ifft scaling) into bufB as even/odd complex, zero-pad ----
    const float s1 = 1.0f / (float)L;
    for (int i = tid; i < L; i += NTH) {
        if (i < (L / 2))
            bufB[i] = make_float2(bufA[2 * i].x * s1, bufA[2 * i + 1].x * s1);
        else
            bufB[i] = make_float2(0.f, 0.f);
    }
    __syncthreads();

    // ---- phase 4: Zk = FFT_8192(packed K) ----
    fft8192(bufB, tw, tid, false);

    // ---- phase 5: Zu = FFT_8192(packed u) ----
    const float2* u2 = (const float2*)(u + (size_t)h * L);
    for (int i = tid; i < L; i += NTH)
        bufA[i] = (i < (L / 2)) ? u2[i] : make_float2(0.f, 0.f);
    __syncthreads();
    fft8192(bufA, tw, tid, false);

    // ---- phase 6: unpack Ud,Kd (rfft of 2L), multiply, repack for half-size c2r IFFT ----
    for (int k = tid; k <= (L / 2); k += NTH) {
        if (k == 0) {
            float2 au = bufA[0], av = bufB[0];
            float U0 = au.x + au.y, UM = au.x - au.y;   // Ud[0], Ud[L]
            float K0 = av.x + av.y, KM = av.x - av.y;
            float P0 = U0 * K0, PM = UM * KM;
            bufA[0] = make_float2(0.5f * (P0 + PM), 0.5f * (P0 - PM));
            continue;
        }
        int k2 = L - k;
        float2 au = bufA[k], bu = bufA[k2];
        float2 av = bufB[k], bv = bufB[k2];
        double ang = -PI_D * (double)k / (double)L;     // -2*pi*k/(2L)
        double sd, cd; sincos(ang, &sd, &cd);
        float wc = (float)cd, ws = (float)sd;           // W^k = e^{-2pi i k/(2L)}
        // Ud[k] = Ze + W^k*Zo
        float2 Zeu = make_float2(0.5f * (au.x + bu.x), 0.5f * (au.y - bu.y));
        float2 dif = make_float2(au.x - bu.x, au.y + bu.y);
        float2 Zou = make_float2(0.5f * dif.y, -0.5f * dif.x);
        float2 Udk = make_float2(Zeu.x + wc * Zou.x - ws * Zou.y,
                                 Zeu.y + wc * Zou.y + ws * Zou.x);
        // Ud[L-k]: W^{L-k} = (-wc, ws)
        float2 Zeu2 = make_float2(0.5f * (bu.x + au.x), 0.5f * (bu.y - au.y));
        float2 dif2 = make_float2(bu.x - au.x, bu.y + au.y);
        float2 Zou2 = make_float2(0.5f * dif2.y, -0.5f * dif2.x);
        float2 Udk2 = make_float2(Zeu2.x - wc * Zou2.x - ws * Zou2.y,
                                  Zeu2.y - wc * Zou2.y + ws * Zou2.x);
        // Kd[k], Kd[L-k]
        float2 Zev = make_float2(0.5f * (av.x + bv.x), 0.5f * (av.y - bv.y));
        float2 dfv = make_float2(av.x - bv.x, av.y + bv.y);
        float2 Zov = make_float2(0.5f * dfv.y, -0.5f * dfv.x);
        float2 Kdk = make_float2(Zev.x + wc * Zov.x - ws * Zov.y,
                                 Zev.y + wc * Zov.y + ws * Zov.x);
        float2 Zev2 = make_float2(0.5f * (bv.x + av.x), 0.5f * (bv.y - av.y));
        float2 dfv2 = make_float2(bv.x - av.x, bv.y + av.y);
        float2 Zov2 = make_float2(0.5f * dfv2.y, -0.5f * dfv2.x);
        float2 Kdk2 = make_float2(Zev2.x - wc * Zov2.x - ws * Zov2.y,
                                  Zev2.y - wc * Zov2.y + ws * Zov2.x);
        // spectrum product
        float2 Pk  = cmulf(Udk,  Kdk);
        float2 Pk2 = cmulf(Udk2, Kdk2);
        // inverse pack: Z[k] = Ze_y + i*Zo_y, Zo_y = (P[k]-conj(P[L-k]))*conj(W^k)/2
        float2 Zey = make_float2(0.5f * (Pk.x + Pk2.x), 0.5f * (Pk.y - Pk2.y));
        float2 dfp = make_float2(Pk.x - Pk2.x, Pk.y + Pk2.y);
        float2 Zoy = make_float2(0.5f * (dfp.x * wc + dfp.y * ws),
                                 0.5f * (dfp.y * wc - dfp.x * ws));
        bufA[k] = make_float2(Zey.x - Zoy.y, Zey.y + Zoy.x);
        // Z[L-k]: conj(W^{L-k}) = (-wc, -ws)
        float2 Zey2 = make_float2(0.5f * (Pk2.x + Pk.x), 0.5f * (Pk2.y - Pk.y));
        float2 dfp2 = make_float2(Pk2.x - Pk.x, Pk2.y + Pk.y);
        float2 Zoy2 = make_float2(0.5f * (-dfp2.x * wc + dfp2.y * ws),
                                  0.5f * (-dfp2.y * wc - dfp2.x * ws));
        if (k2 != k)
            bufA[k2] = make_float2(Zey2.x - Zoy2.y, Zey2.y + Zoy2.x);
    }
    __syncthreads();

    // ---- phase 7: half-size complex IFFT -> y interleaved; add D*u; store ----
    fft8192(bufA, tw, tid, true);
    const float2* urow = (const float2*)(u + (size_t)h * L);
    float2* orow = (float2*)(out + (size_t)h * L);
    for (int i = tid; i < (L / 2); i += NTH) {
        float2 z = bufA[i];
        float2 uu = urow[i];
        orow[i] = make_float2(z.x * s1 + Dh * uu.x,
                              z.y * s1 + Dh * uu.y);
    }
}

extern "C" void kernel_launch(void* const* d_in, const int* in_sizes, int n_in,
                              void* d_out, int out_size, void* d_ws, size_t ws_size,
                              hipStream_t stream) {
    (void)in_sizes; (void)n_in; (void)d_ws; (void)ws_size; (void)out_size;
    const float* u        = (const float*)d_in[0];
    const float* Ct_ri    = (const float*)d_in[1];
    const float* B_raw    = (const float*)d_in[2];
    const float* Dp       = (const float*)d_in[3];
    const float* log_step = (const float*)d_in[4];
    const float* Lre      = (const float*)d_in[5];
    const float* Lim      = (const float*)d_in[6];
    const float* p_re     = (const float*)d_in[7];
    const float* p_im     = (const float*)d_in[8];
    const float* q_re     = (const float*)d_in[9];
    const float* q_im     = (const float*)d_in[10];
    const float* Vc_re    = (const float*)d_in[11];
    const float* Vc_im    = (const float*)d_in[12];
    float* out = (float*)d_out;

    // LDS: 2*8192 complex bufs + 2048 twiddles + 4*64 weights (float2) + 128 floats
    const size_t smem = (size_t)(2 * L + 2048 + 4 * NSTATE) * sizeof(float2)
                      + 2 * NSTATE * sizeof(float);
    hipFuncSetAttribute((const void*)s4_fused_kernel,
                        hipFuncAttributeMaxDynamicSharedMemorySize, (int)smem);
    s4_fused_kernel<<<dim3(H), dim3(NTH), smem, stream>>>(
        u, Ct_ri, B_raw, Dp, log_step, Lre, Lim,
        p_re, p_im, q_re, q_im, Vc_re, Vc_im, out);
}

// Round 2
// 166.344 us; speedup vs baseline: 1.6560x; 1.6560x over previous
//
#include <hip/hip_runtime.h>
#include <math.h>

#define H 128
#define L 8192
#define NSTATE 64
#define NTH 1024
#define LPT (L / NTH)
#define PI_D 3.14159265358979323846
#define RT2 0.70710678118654752440f

__device__ __forceinline__ int SWZ(int e) { return e ^ ((e >> 3) & 7); }
__device__ __forceinline__ int TSW(int j) { return j ^ ((j >> 4) & 15) ^ ((j >> 8) & 15); }
__device__ __forceinline__ int brev13(int x) { return (int)(__brev((unsigned)x) >> 19); }

__device__ __forceinline__ float2 cmul(float2 a, float2 b) {
    return make_float2(a.x * b.x - a.y * b.y, a.x * b.y + a.y * b.x);
}
__device__ __forceinline__ float2 cadd(float2 a, float2 b) { return make_float2(a.x + b.x, a.y + b.y); }
__device__ __forceinline__ float2 csub(float2 a, float2 b) { return make_float2(a.x - b.x, a.y - b.y); }
__device__ __forceinline__ float2 mnegi(float2 a) { return make_float2(a.y, -a.x); }  // a * (-i)
__device__ __forceinline__ float2 mposi(float2 a) { return make_float2(-a.y, a.x); }  // a * (+i)

// W_N^idx for idx in [0,4096); INV -> conjugate (inverse transform)
template<bool INV>
__device__ __forceinline__ float2 twget(const float2* __restrict__ tw, int idx) {
    float2 w;
    if (idx < 2048) w = tw[TSW(idx)];
    else { float2 t = tw[TSW(idx - 2048)]; w = make_float2(t.y, -t.x); }  // * (-i)
    if (INV) w.y = -w.y;
    return w;
}

// ---- forward DIF fused pair (stage sizes 4*SIGMA then 2*SIGMA), dual buffer ----
template<int SIGMA>
__device__ __forceinline__ void dif_pass2(float2* __restrict__ A, float2* __restrict__ B,
                                          const float2* __restrict__ tw, int tid) {
    const int m1 = 2048 / SIGMA;
    #pragma unroll
    for (int rep = 0; rep < 2; ++rep) {
        int q = tid + rep * NTH;
        int r = q & (SIGMA - 1);
        int b = ((q & ~(SIGMA - 1)) << 2) | r;
        float2 w1 = twget<false>(tw, r * m1);        // W_{4s}^r
        float2 w2 = twget<false>(tw, 2 * r * m1);    // W_{2s}^r
        float2 w1b = mnegi(w1);                      // W_{4s}^{r+s}
        int i0 = SWZ(b), i1 = SWZ(b + SIGMA), i2 = SWZ(b + 2 * SIGMA), i3 = SWZ(b + 3 * SIGMA);
        {
            float2 x0 = A[i0], x1 = A[i1], x2 = A[i2], x3 = A[i3];
            float2 y0 = cadd(x0, x2), y2 = cmul(csub(x0, x2), w1);
            float2 y1 = cadd(x1, x3), y3 = cmul(csub(x1, x3), w1b);
            A[i0] = cadd(y0, y1); A[i1] = cmul(csub(y0, y1), w2);
            A[i2] = cadd(y2, y3); A[i3] = cmul(csub(y2, y3), w2);
        }
        {
            float2 x0 = B[i0], x1 = B[i1], x2 = B[i2], x3 = B[i3];
            float2 y0 = cadd(x0, x2), y2 = cmul(csub(x0, x2), w1);
            float2 y1 = cadd(x1, x3), y3 = cmul(csub(x1, x3), w1b);
            B[i0] = cadd(y0, y1); B[i1] = cmul(csub(y0, y1), w2);
            B[i2] = cadd(y2, y3); B[i3] = cmul(csub(y2, y3), w2);
        }
    }
}

// ---- forward DIF radix-8 final pass (stage sizes 8,4,2), one 8-block ----
__device__ __forceinline__ void dif_r8_one(float2* __restrict__ A, int base) {
    float2 x0 = A[SWZ(base + 0)], x1 = A[SWZ(base + 1)], x2 = A[SWZ(base + 2)], x3 = A[SWZ(base + 3)];
    float2 x4 = A[SWZ(base + 4)], x5 = A[SWZ(base + 5)], x6 = A[SWZ(base + 6)], x7 = A[SWZ(base + 7)];
    float2 a0 = cadd(x0, x4), a1 = cadd(x1, x5), a2 = cadd(x2, x6), a3 = cadd(x3, x7);
    float2 s0 = csub(x0, x4), s1 = csub(x1, x5), s2 = csub(x2, x6), s3 = csub(x3, x7);
    float2 b0 = s0;
    float2 b1 = cmul(s1, make_float2(RT2, -RT2));
    float2 b2 = mnegi(s2);
    float2 b3 = cmul(s3, make_float2(-RT2, -RT2));
    float2 c0 = cadd(a0, a2), c2 = csub(a0, a2);
    float2 c1 = cadd(a1, a3), c3 = mnegi(csub(a1, a3));
    float2 d0 = cadd(b0, b2), d2 = csub(b0, b2);
    float2 d1 = cadd(b1, b3), d3 = mnegi(csub(b1, b3));
    A[SWZ(base + 0)] = cadd(c0, c1); A[SWZ(base + 1)] = csub(c0, c1);
    A[SWZ(base + 2)] = cadd(c2, c3); A[SWZ(base + 3)] = csub(c2, c3);
    A[SWZ(base + 4)] = cadd(d0, d1); A[SWZ(base + 5)] = csub(d0, d1);
    A[SWZ(base + 6)] = cadd(d2, d3); A[SWZ(base + 7)] = csub(d2, d3);
}

// ---- inverse DIT radix-8 first pass (stage sizes 2,4,8), one 8-block ----
__device__ __forceinline__ void dit_r8_one(float2* __restrict__ A, int base) {
    float2 x0 = A[SWZ(base + 0)], x1 = A[SWZ(base + 1)], x2 = A[SWZ(base + 2)], x3 = A[SWZ(base + 3)];
    float2 x4 = A[SWZ(base + 4)], x5 = A[SWZ(base + 5)], x6 = A[SWZ(base + 6)], x7 = A[SWZ(base + 7)];
    float2 a0 = cadd(x0, x1), a1 = csub(x0, x1), a2 = cadd(x2, x3), a3 = csub(x2, x3);
    float2 a4 = cadd(x4, x5), a5 = csub(x4, x5), a6 = cadd(x6, x7), a7 = csub(x6, x7);
    float2 b0 = cadd(a0, a2), b2 = csub(a0, a2);
    float2 t13 = mposi(a3); float2 b1 = cadd(a1, t13), b3 = csub(a1, t13);
    float2 b4 = cadd(a4, a6), b6 = csub(a4, a6);
    float2 t57 = mposi(a7); float2 b5 = cadd(a5, t57), b7 = csub(a5, t57);
    float2 t4 = b4;
    float2 t5 = cmul(make_float2(RT2, RT2), b5);
    float2 t6 = mposi(b6);
    float2 t7 = cmul(make_float2(-RT2, RT2), b7);
    A[SWZ(base + 0)] = cadd(b0, t4); A[SWZ(base + 4)] = csub(b0, t4);
    A[SWZ(base + 1)] = cadd(b1, t5); A[SWZ(base + 5)] = csub(b1, t5);
    A[SWZ(base + 2)] = cadd(b2, t6); A[SWZ(base + 6)] = csub(b2, t6);
    A[SWZ(base + 3)] = cadd(b3, t7); A[SWZ(base + 7)] = csub(b3, t7);
}

// ---- inverse DIT fused pair (stage halves SIGMA then 2*SIGMA), single buffer ----
template<int SIGMA>
__device__ __forceinline__ void dit_pass1(float2* __restrict__ A,
                                          const float2* __restrict__ tw, int tid) {
    const int m1 = 2048 / SIGMA;
    #pragma unroll
    for (int rep = 0; rep < 2; ++rep) {
        int q = tid + rep * NTH;
        int r = q & (SIGMA - 1);
        int b = ((q & ~(SIGMA - 1)) << 2) | r;
        float2 w1 = twget<true>(tw, 2 * r * m1);     // conj W_{2s}^r
        float2 w2 = twget<true>(tw, r * m1);         // conj W_{4s}^r
        float2 w2b = mposi(w2);                      // conj W_{4s}^{r+s}
        int i0 = SWZ(b), i1 = SWZ(b + SIGMA), i2 = SWZ(b + 2 * SIGMA), i3 = SWZ(b + 3 * SIGMA);
        float2 x0 = A[i0], x1 = A[i1], x2 = A[i2], x3 = A[i3];
        float2 t1 = cmul(w1, x1);
        float2 y0 = cadd(x0, t1), y1 = csub(x0, t1);
        float2 t3 = cmul(w1, x3);
        float2 y2 = cadd(x2, t3), y3 = csub(x2, t3);
        float2 u2 = cmul(w2, y2);
        A[i0] = cadd(y0, u2); A[i2] = csub(y0, u2);
        float2 u3 = cmul(w2b, y3);
        A[i1] = cadd(y1, u3); A[i3] = csub(y1, u3);
    }
}

// inverse FFT: bit-reversed input -> natural output (unscaled)
__device__ __forceinline__ void fft_dit_inv(float2* __restrict__ A,
                                            const float2* __restrict__ tw, int tid) {
    dit_r8_one(A, tid * 8);      __syncthreads();
    dit_pass1<8>(A, tw, tid);    __syncthreads();
    dit_pass1<32>(A, tw, tid);   __syncthreads();
    dit_pass1<128>(A, tw, tid);  __syncthreads();
    dit_pass1<512>(A, tw, tid);  __syncthreads();
    dit_pass1<2048>(A, tw, tid); __syncthreads();
}

// forward FFT on two buffers at once: natural input -> bit-reversed output
__device__ __forceinline__ void fft_dif_dual(float2* __restrict__ A, float2* __restrict__ B,
                                             const float2* __restrict__ tw, int tid) {
    dif_pass2<2048>(A, B, tw, tid); __syncthreads();
    dif_pass2<512>(A, B, tw, tid);  __syncthreads();
    dif_pass2<128>(A, B, tw, tid);  __syncthreads();
    dif_pass2<32>(A, B, tw, tid);   __syncthreads();
    dif_pass2<8>(A, B, tw, tid);    __syncthreads();
    dif_r8_one(A, tid * 8); dif_r8_one(B, tid * 8); __syncthreads();
}

extern __shared__ char smem_raw[];

__global__ __launch_bounds__(NTH)
void s4_fused_kernel(const float* __restrict__ u,
                     const float* __restrict__ Ct_ri,
                     const float* __restrict__ B_raw,
                     const float* __restrict__ Dp,
                     const float* __restrict__ log_step,
                     const float* __restrict__ Lre_g,
                     const float* __restrict__ Lim_g,
                     const float* __restrict__ p_re,
                     const float* __restrict__ p_im,
                     const float* __restrict__ q_re,
                     const float* __restrict__ q_im,
                     const float* __restrict__ Vc_re,
                     const float* __restrict__ Vc_im,
                     float* __restrict__ out)
{
    float2* bufA = (float2*)smem_raw;          // 8192 complex (swizzled layout)
    float2* bufB = bufA + L;                   // 8192 complex
    float2* tw   = bufB + L;                   // 2048 complex twiddles (swizzled)
    float2* w00  = tw + 2048;
    float2* w01  = w00 + NSTATE;
    float2* w10  = w01 + NSTATE;
    float2* w11  = w10 + NSTATE;
    float*  wdre  = (float*)(w11 + NSTATE);    // -Lambda_re
    float*  wdre2 = wdre + NSTATE;             // (-Lambda_re)^2
    float*  wlim  = wdre2 + NSTATE;            // Lambda_im

    const int h   = blockIdx.x;
    const int tid = threadIdx.x;

    // ---- setup: twiddle table ----
    for (int j = tid; j < 2048; j += NTH) {
        double a = -2.0 * PI_D * (double)j / (double)L;
        tw[TSW(j)] = make_float2((float)cos(a), (float)sin(a));
    }
    // ---- setup: per-channel Cauchy weights ----
    if (tid < NSTATE) {
        int n = tid;
        float2 Bc = make_float2(0.f, 0.f);
        for (int m = 0; m < NSTATE; ++m) {
            float br = B_raw[h * NSTATE + m];
            Bc.x += Vc_re[n * NSTATE + m] * br;
            Bc.y += Vc_im[n * NSTATE + m] * br;
        }
        float2 Ctc = make_float2(Ct_ri[(h * NSTATE + n) * 2 + 0],
                                 -Ct_ri[(h * NSTATE + n) * 2 + 1]);
        float2 pc = make_float2(p_re[n], p_im[n]);
        float2 qc = make_float2(q_re[n], -q_im[n]);
        w00[n] = cmul(Ctc, Bc);
        w01[n] = cmul(Ctc, pc);
        w10[n] = cmul(qc, Bc);
        w11[n] = cmul(qc, pc);
        float dre = -Lre_g[n];
        wdre[n] = dre;
        wdre2[n] = dre * dre;
        wlim[n] = Lim_g[n];
    }
    __syncthreads();

    const float step = expf(log_step[h]);
    const float two_over_step = 2.0f / step;
    const float Dh = Dp[h];

    // ---- phase 1: at_roots for frequency l=brev(p), deposited at position p ----
    // g = i*(2/step)*tan(pi*l/L); c = 1 + i*tan(pi*l/L)
    for (int il = 0; il < LPT; ++il) {
        int p = tid + il * NTH;
        int l = brev13(p);
        double th = PI_D * (double)l / (double)L;
        float t = (float)tan(th);
        t = fminf(fmaxf(t, -3.0e7f), 3.0e7f);
        float gi = two_over_step * t;
        float2 a00 = make_float2(0.f, 0.f), a01 = a00, a10 = a00, a11 = a00;
        for (int n = 0; n < NSTATE; ++n) {
            float dre = wdre[n];
            float dim = gi - wlim[n];
            float den = fmaf(dim, dim, wdre2[n]);
            float inv = __builtin_amdgcn_rcpf(den);
            float rre = dre * inv;
            float rim = -dim * inv;
            float2 c00 = w00[n], c01 = w01[n], c10 = w10[n], c11 = w11[n];
            a00.x += c00.x * rre - c00.y * rim; a00.y += c00.x * rim + c00.y * rre;
            a01.x += c01.x * rre - c01.y * rim; a01.y += c01.x * rim + c01.y * rre;
            a10.x += c10.x * rre - c10.y * rim; a10.y += c10.x * rim + c10.y * rre;
            a11.x += c11.x * rre - c11.y * rim; a11.y += c11.x * rim + c11.y * rre;
        }
        float2 den1 = make_float2(1.0f + a11.x, a11.y);
        float inv = 1.0f / (den1.x * den1.x + den1.y * den1.y);
        float2 qn = cmul(a01, a10);
        float2 dv = make_float2((qn.x * den1.x + qn.y * den1.y) * inv,
                                (qn.y * den1.x - qn.x * den1.y) * inv);
        float2 tmp = make_float2(a00.x - dv.x, a00.y - dv.y);
        float2 c = make_float2(1.0f, t);
        bufA[SWZ(p)] = cmul(c, tmp);
    }
    __syncthreads();

    // ---- phase 2: K = IFFT_L(at_roots), bitrev input -> natural K ----
    fft_dit_inv(bufA, tw, tid);

    // ---- phase 3: pack K (with 1/L scaling) into bufB, zero-pad ----
    const float s1 = 1.0f / (float)L;
    for (int i = tid; i < L; i += NTH) {
        if (i < (L / 2))
            bufB[SWZ(i)] = make_float2(bufA[SWZ(2 * i)].x * s1, bufA[SWZ(2 * i + 1)].x * s1);
        else
            bufB[SWZ(i)] = make_float2(0.f, 0.f);
    }
    __syncthreads();

    // ---- phase 4: load packed u into bufA ----
    const float2* u2 = (const float2*)(u + (size_t)h * L);
    for (int i = tid; i < L; i += NTH)
        bufA[SWZ(i)] = (i < (L / 2)) ? u2[i] : make_float2(0.f, 0.f);
    __syncthreads();

    // ---- phase 5: forward DIF on both buffers (Zu in A, Zk in B), bitrev order ----
    fft_dif_dual(bufA, bufB, tw, tid);

    // ---- phase 6: unpack rfft(2L) spectra, multiply, repack; all in bitrev domain ----
    for (int k = tid; k <= (L / 2); k += NTH) {
        if (k == 0) {
            float2 au = bufA[0], av = bufB[0];
            float U0 = au.x + au.y, UM = au.x - au.y;
            float K0 = av.x + av.y, KM = av.x - av.y;
            float P0 = U0 * K0, PM = UM * KM;
            bufA[0] = make_float2(0.5f * (P0 + PM), 0.5f * (P0 - PM));
            continue;
        }
        int k2 = L - k;
        int pa = SWZ(brev13(k)), pb = SWZ(brev13(k2));
        float2 au = bufA[pa], bu = bufA[pb];
        float2 av = bufB[pa], bv = bufB[pb];
        double ang = -PI_D * (double)k / (double)L;
        double sd, cd; sincos(ang, &sd, &cd);
        float wc = (float)cd, ws = (float)sd;
        float2 Zeu = make_float2(0.5f * (au.x + bu.x), 0.5f * (au.y - bu.y));
        float2 dif = make_float2(au.x - bu.x, au.y + bu.y);
        float2 Zou = make_float2(0.5f * dif.y, -0.5f * dif.x);
        float2 Udk = make_float2(Zeu.x + wc * Zou.x - ws * Zou.y,
                                 Zeu.y + wc * Zou.y + ws * Zou.x);
        float2 Zeu2 = make_float2(0.5f * (bu.x + au.x), 0.5f * (bu.y - au.y));
        float2 dif2 = make_float2(bu.x - au.x, bu.y + au.y);
        float2 Zou2 = make_float2(0.5f * dif2.y, -0.5f * dif2.x);
        float2 Udk2 = make_float2(Zeu2.x - wc * Zou2.x - ws * Zou2.y,
                                  Zeu2.y - wc * Zou2.y + ws * Zou2.x);
        float2 Zev = make_float2(0.5f * (av.x + bv.x), 0.5f * (av.y - bv.y));
        float2 dfv = make_float2(av.x - bv.x, av.y + bv.y);
        float2 Zov = make_float2(0.5f * dfv.y, -0.5f * dfv.x);
        float2 Kdk = make_float2(Zev.x + wc * Zov.x - ws * Zov.y,
                                 Zev.y + wc * Zov.y + ws * Zov.x);
        float2 Zev2 = make_float2(0.5f * (bv.x + av.x), 0.5f * (bv.y - av.y));
        float2 dfv2 = make_float2(bv.x - av.x, bv.y + av.y);
        float2 Zov2 = make_float2(0.5f * dfv2.y, -0.5f * dfv2.x);
        float2 Kdk2 = make_float2(Zev2.x - wc * Zov2.x - ws * Zov2.y,
                                  Zev2.y - wc * Zov2.y + ws * Zov2.x);
        float2 Pk  = cmul(Udk,  Kdk);
        float2 Pk2 = cmul(Udk2, Kdk2);
        float2 Zey = make_float2(0.5f * (Pk.x + Pk2.x), 0.5f * (Pk.y - Pk2.y));
        float2 dfp = make_float2(Pk.x - Pk2.x, Pk.y + Pk2.y);
        float2 Zoy = make_float2(0.5f * (dfp.x * wc + dfp.y * ws),
                                 0.5f * (dfp.y * wc - dfp.x * ws));
        bufA[pa] = make_float2(Zey.x - Zoy.y, Zey.y + Zoy.x);
        float2 Zey2 = make_float2(0.5f * (Pk2.x + Pk.x), 0.5f * (Pk2.y - Pk.y));
        float2 dfp2 = make_float2(Pk2.x - Pk.x, Pk2.y + Pk.y);
        float2 Zoy2 = make_float2(0.5f * (-dfp2.x * wc + dfp2.y * ws),
                                  0.5f * (-dfp2.y * wc - dfp2.x * ws));
        if (k2 != k)
            bufA[pb] = make_float2(Zey2.x - Zoy2.y, Zey2.y + Zoy2.x);
    }
    __syncthreads();

    // ---- phase 7: inverse DIT -> y pairs natural; add D*u; store ----
    fft_dit_inv(bufA, tw, tid);
    const float2* urow = (const float2*)(u + (size_t)h * L);
    float2* orow = (float2*)(out + (size_t)h * L);
    for (int i = tid; i < (L / 2); i += NTH) {
        float2 z = bufA[SWZ(i)];
        float2 uu = urow[i];
        orow[i] = make_float2(z.x * s1 + Dh * uu.x,
                              z.y * s1 + Dh * uu.y);
    }
}

extern "C" void kernel_launch(void* const* d_in, const int* in_sizes, int n_in,
                              void* d_out, int out_size, void* d_ws, size_t ws_size,
                              hipStream_t stream) {
    (void)in_sizes; (void)n_in; (void)d_ws; (void)ws_size; (void)out_size;
    const float* u        = (const float*)d_in[0];
    const float* Ct_ri    = (const float*)d_in[1];
    const float* B_raw    = (const float*)d_in[2];
    const float* Dp       = (const float*)d_in[3];
    const float* log_step = (const float*)d_in[4];
    const float* Lre      = (const float*)d_in[5];
    const float* Lim      = (const float*)d_in[6];
    const float* p_re     = (const float*)d_in[7];
    const float* p_im     = (const float*)d_in[8];
    const float* q_re     = (const float*)d_in[9];
    const float* q_im     = (const float*)d_in[10];
    const float* Vc_re    = (const float*)d_in[11];
    const float* Vc_im    = (const float*)d_in[12];
    float* out = (float*)d_out;

    const size_t smem = (size_t)(2 * L + 2048 + 4 * NSTATE) * sizeof(float2)
                      + 3 * NSTATE * sizeof(float);
    hipFuncSetAttribute((const void*)s4_fused_kernel,
                        hipFuncAttributeMaxDynamicSharedMemorySize, (int)smem);
    s4_fused_kernel<<<dim3(H), dim3(NTH), smem, stream>>>(
        u, Ct_ri, B_raw, Dp, log_step, Lre, Lim,
        p_re, p_im, q_re, q_im, Vc_re, Vc_im, out);
}

// Round 3
// 158.995 us; speedup vs baseline: 1.7325x; 1.0462x over previous
//
#include <hip/hip_runtime.h>
#include <math.h>

#define H 128
#define L 8192
#define NSTATE 64
#define NTH 1024
#define LPT (L / NTH)
#define PI_D 3.14159265358979323846
#define RT2 0.70710678118654752440f

// W_16384 = e^{-i*pi/8192}
#define W16K_RE 0.99999992646571789f
#define W16K_IM (-3.8349518757139556e-4f)

__device__ __forceinline__ int SWZ(int e) { return e ^ ((e >> 3) & 7); }
__device__ __forceinline__ int TSW(int j) { return j ^ ((j >> 4) & 15) ^ ((j >> 8) & 15); }
__device__ __forceinline__ int brev13(int x) { return (int)(__brev((unsigned)x) >> 19); }

__device__ __forceinline__ float2 cmul(float2 a, float2 b) {
    return make_float2(a.x * b.x - a.y * b.y, a.x * b.y + a.y * b.x);
}
__device__ __forceinline__ float2 cadd(float2 a, float2 b) { return make_float2(a.x + b.x, a.y + b.y); }
__device__ __forceinline__ float2 csub(float2 a, float2 b) { return make_float2(a.x - b.x, a.y - b.y); }
__device__ __forceinline__ float2 mnegi(float2 a) { return make_float2(a.y, -a.x); }  // a * (-i)
__device__ __forceinline__ float2 mposi(float2 a) { return make_float2(-a.y, a.x); }  // a * (+i)

// W_8192^idx for idx in [0,4096); INV -> conjugate
template<bool INV>
__device__ __forceinline__ float2 twget(const float2* __restrict__ tw, int idx) {
    float2 w;
    if (idx < 2048) w = tw[TSW(idx)];
    else { float2 t = tw[TSW(idx - 2048)]; w = make_float2(t.y, -t.x); }  // * (-i)
    if (INV) w.y = -w.y;
    return w;
}

// ---- forward DIF fused pair (stage sizes 4*SIGMA then 2*SIGMA), single buffer ----
template<int SIGMA>
__device__ __forceinline__ void dif_pass1(float2* __restrict__ A,
                                          const float2* __restrict__ tw, int tid) {
    const int m1 = 2048 / SIGMA;
    #pragma unroll
    for (int rep = 0; rep < 2; ++rep) {
        int q = tid + rep * NTH;
        int r = q & (SIGMA - 1);
        int b = ((q & ~(SIGMA - 1)) << 2) | r;
        float2 w1 = twget<false>(tw, r * m1);        // W_{4s}^r
        float2 w2 = twget<false>(tw, 2 * r * m1);    // W_{2s}^r
        float2 w1b = mnegi(w1);                      // W_{4s}^{r+s}
        int i0 = SWZ(b), i1 = SWZ(b + SIGMA), i2 = SWZ(b + 2 * SIGMA), i3 = SWZ(b + 3 * SIGMA);
        float2 x0 = A[i0], x1 = A[i1], x2 = A[i2], x3 = A[i3];
        float2 y0 = cadd(x0, x2), y2 = cmul(csub(x0, x2), w1);
        float2 y1 = cadd(x1, x3), y3 = cmul(csub(x1, x3), w1b);
        A[i0] = cadd(y0, y1); A[i1] = cmul(csub(y0, y1), w2);
        A[i2] = cadd(y2, y3); A[i3] = cmul(csub(y2, y3), w2);
    }
}

// ---- forward DIF radix-8 final pass (stage sizes 8,4,2), one 8-block ----
__device__ __forceinline__ void dif_r8_one(float2* __restrict__ A, int base) {
    float2 x0 = A[SWZ(base + 0)], x1 = A[SWZ(base + 1)], x2 = A[SWZ(base + 2)], x3 = A[SWZ(base + 3)];
    float2 x4 = A[SWZ(base + 4)], x5 = A[SWZ(base + 5)], x6 = A[SWZ(base + 6)], x7 = A[SWZ(base + 7)];
    float2 a0 = cadd(x0, x4), a1 = cadd(x1, x5), a2 = cadd(x2, x6), a3 = cadd(x3, x7);
    float2 s0 = csub(x0, x4), s1 = csub(x1, x5), s2 = csub(x2, x6), s3 = csub(x3, x7);
    float2 b0 = s0;
    float2 b1 = cmul(s1, make_float2(RT2, -RT2));
    float2 b2 = mnegi(s2);
    float2 b3 = cmul(s3, make_float2(-RT2, -RT2));
    float2 c0 = cadd(a0, a2), c2 = csub(a0, a2);
    float2 c1 = cadd(a1, a3), c3 = mnegi(csub(a1, a3));
    float2 d0 = cadd(b0, b2), d2 = csub(b0, b2);
    float2 d1 = cadd(b1, b3), d3 = mnegi(csub(b1, b3));
    A[SWZ(base + 0)] = cadd(c0, c1); A[SWZ(base + 1)] = csub(c0, c1);
    A[SWZ(base + 2)] = cadd(c2, c3); A[SWZ(base + 3)] = csub(c2, c3);
    A[SWZ(base + 4)] = cadd(d0, d1); A[SWZ(base + 5)] = csub(d0, d1);
    A[SWZ(base + 6)] = cadd(d2, d3); A[SWZ(base + 7)] = csub(d2, d3);
}

// ---- inverse DIT radix-8 first pass (stage sizes 2,4,8), one 8-block ----
__device__ __forceinline__ void dit_r8_one(float2* __restrict__ A, int base) {
    float2 x0 = A[SWZ(base + 0)], x1 = A[SWZ(base + 1)], x2 = A[SWZ(base + 2)], x3 = A[SWZ(base + 3)];
    float2 x4 = A[SWZ(base + 4)], x5 = A[SWZ(base + 5)], x6 = A[SWZ(base + 6)], x7 = A[SWZ(base + 7)];
    float2 a0 = cadd(x0, x1), a1 = csub(x0, x1), a2 = cadd(x2, x3), a3 = csub(x2, x3);
    float2 a4 = cadd(x4, x5), a5 = csub(x4, x5), a6 = cadd(x6, x7), a7 = csub(x6, x7);
    float2 b0 = cadd(a0, a2), b2 = csub(a0, a2);
    float2 t13 = mposi(a3); float2 b1 = cadd(a1, t13), b3 = csub(a1, t13);
    float2 b4 = cadd(a4, a6), b6 = csub(a4, a6);
    float2 t57 = mposi(a7); float2 b5 = cadd(a5, t57), b7 = csub(a5, t57);
    float2 t4 = b4;
    float2 t5 = cmul(make_float2(RT2, RT2), b5);
    float2 t6 = mposi(b6);
    float2 t7 = cmul(make_float2(-RT2, RT2), b7);
    A[SWZ(base + 0)] = cadd(b0, t4); A[SWZ(base + 4)] = csub(b0, t4);
    A[SWZ(base + 1)] = cadd(b1, t5); A[SWZ(base + 5)] = csub(b1, t5);
    A[SWZ(base + 2)] = cadd(b2, t6); A[SWZ(base + 6)] = csub(b2, t6);
    A[SWZ(base + 3)] = cadd(b3, t7); A[SWZ(base + 7)] = csub(b3, t7);
}

// ---- inverse DIT fused pair (stage halves SIGMA then 2*SIGMA) ----
template<int SIGMA>
__device__ __forceinline__ void dit_pass1(float2* __restrict__ A,
                                          const float2* __restrict__ tw, int tid) {
    const int m1 = 2048 / SIGMA;
    #pragma unroll
    for (int rep = 0; rep < 2; ++rep) {
        int q = tid + rep * NTH;
        int r = q & (SIGMA - 1);
        int b = ((q & ~(SIGMA - 1)) << 2) | r;
        float2 w1 = twget<true>(tw, 2 * r * m1);     // conj W_{2s}^r
        float2 w2 = twget<true>(tw, r * m1);         // conj W_{4s}^r
        float2 w2b = mposi(w2);                      // conj W_{4s}^{r+s}
        int i0 = SWZ(b), i1 = SWZ(b + SIGMA), i2 = SWZ(b + 2 * SIGMA), i3 = SWZ(b + 3 * SIGMA);
        float2 x0 = A[i0], x1 = A[i1], x2 = A[i2], x3 = A[i3];
        float2 t1 = cmul(w1, x1);
        float2 y0 = cadd(x0, t1), y1 = csub(x0, t1);
        float2 t3 = cmul(w1, x3);
        float2 y2 = cadd(x2, t3), y3 = csub(x2, t3);
        float2 u2 = cmul(w2, y2);
        A[i0] = cadd(y0, u2); A[i2] = csub(y0, u2);
        float2 u3 = cmul(w2b, y3);
        A[i1] = cadd(y1, u3); A[i3] = csub(y1, u3);
    }
}

// inverse FFT: bit-reversed input -> natural output (unscaled)
__device__ __forceinline__ void fft_dit_inv(float2* __restrict__ A,
                                            const float2* __restrict__ tw, int tid) {
    dit_r8_one(A, tid * 8);      __syncthreads();
    dit_pass1<8>(A, tw, tid);    __syncthreads();
    dit_pass1<32>(A, tw, tid);   __syncthreads();
    dit_pass1<128>(A, tw, tid);  __syncthreads();
    dit_pass1<512>(A, tw, tid);  __syncthreads();
    dit_pass1<2048>(A, tw, tid); __syncthreads();
}

// forward FFT: natural input -> bit-reversed output
__device__ __forceinline__ void fft_dif_single(float2* __restrict__ A,
                                               const float2* __restrict__ tw, int tid) {
    dif_pass1<2048>(A, tw, tid); __syncthreads();
    dif_pass1<512>(A, tw, tid);  __syncthreads();
    dif_pass1<128>(A, tw, tid);  __syncthreads();
    dif_pass1<32>(A, tw, tid);   __syncthreads();
    dif_pass1<8>(A, tw, tid);    __syncthreads();
    dif_r8_one(A, tid * 8);      __syncthreads();
}

extern __shared__ char smem_raw[];

// Grid = 256: blocks 0..127 cyclic part (type 0), 128..255 negacyclic (type 1).
// y = 0.5*(cyclic + negacyclic) + D*u, combined via atomicAdd on zeroed out.
__global__ __launch_bounds__(NTH)
void s4_split_kernel(const float* __restrict__ u,
                     const float* __restrict__ Ct_ri,
                     const float* __restrict__ B_raw,
                     const float* __restrict__ Dp,
                     const float* __restrict__ log_step,
                     const float* __restrict__ Lre_g,
                     const float* __restrict__ Lim_g,
                     const float* __restrict__ p_re,
                     const float* __restrict__ p_im,
                     const float* __restrict__ q_re,
                     const float* __restrict__ q_im,
                     const float* __restrict__ Vc_re,
                     const float* __restrict__ Vc_im,
                     float* __restrict__ out)
{
    float2* bufA = (float2*)smem_raw;          // 8192 complex (swizzled)
    float2* spec = bufA + L;                   // 8192 complex (swizzled, bitrev domain)
    float2* tw   = spec + L;                   // 2048 complex twiddles (swizzled)
    float2* w00  = tw + 2048;
    float2* w01  = w00 + NSTATE;
    float2* w10  = w01 + NSTATE;
    float2* w11  = w10 + NSTATE;
    float*  wdre  = (float*)(w11 + NSTATE);
    float*  wdre2 = wdre + NSTATE;
    float*  wlim  = wdre2 + NSTATE;

    const int bid  = blockIdx.x;
    const int type = bid >> 7;          // 0 = cyclic, 1 = negacyclic
    const int h    = bid & (H - 1);
    const int tid  = threadIdx.x;

    // ---- setup: twiddle table ----
    for (int j = tid; j < 2048; j += NTH) {
        double a = -2.0 * PI_D * (double)j / (double)L;
        tw[TSW(j)] = make_float2((float)cos(a), (float)sin(a));
    }
    // ---- setup: per-channel Cauchy weights ----
    if (tid < NSTATE) {
        int n = tid;
        float2 Bc = make_float2(0.f, 0.f);
        for (int m = 0; m < NSTATE; ++m) {
            float br = B_raw[h * NSTATE + m];
            Bc.x += Vc_re[n * NSTATE + m] * br;
            Bc.y += Vc_im[n * NSTATE + m] * br;
        }
        float2 Ctc = make_float2(Ct_ri[(h * NSTATE + n) * 2 + 0],
                                 -Ct_ri[(h * NSTATE + n) * 2 + 1]);
        float2 pc = make_float2(p_re[n], p_im[n]);
        float2 qc = make_float2(q_re[n], -q_im[n]);
        w00[n] = cmul(Ctc, Bc);
        w01[n] = cmul(Ctc, pc);
        w10[n] = cmul(qc, Bc);
        w11[n] = cmul(qc, pc);
        float dre = -Lre_g[n];
        wdre[n] = dre;
        wdre2[n] = dre * dre;
        wlim[n] = Lim_g[n];
    }
    __syncthreads();

    const float step = expf(log_step[h]);
    const float two_over_step = 2.0f / step;
    const float Dh = Dp[h];
    const float* ur = u + (size_t)h * L;
    const float2 W16K = make_float2(W16K_RE, W16K_IM);

    // ---- load u (type1: twisted by w[t]=e^{-i pi t/L}) into bufA, natural order ----
    for (int i = tid; i < L; i += NTH) {
        float uv = ur[i];
        if (type == 0) {
            bufA[SWZ(i)] = make_float2(uv, 0.f);
        } else {
            float2 w = twget<false>(tw, i >> 1);
            if (i & 1) w = cmul(w, W16K);
            bufA[SWZ(i)] = make_float2(uv * w.x, uv * w.y);
        }
    }

    // ---- Cauchy: evaluate generating fn at freq k (+0.5 for type1), deposit bitrev ----
    const double hoff = type ? 0.5 : 0.0;
    for (int il = 0; il < LPT; ++il) {
        int k = tid + il * NTH;
        double th = PI_D * ((double)k + hoff) / (double)L;
        float t = (float)tan(th);
        t = fminf(fmaxf(t, -3.0e7f), 3.0e7f);   // only type0 k=L/2 clamps
        float gi = two_over_step * t;
        float2 a00 = make_float2(0.f, 0.f), a01 = a00, a10 = a00, a11 = a00;
        for (int n = 0; n < NSTATE; ++n) {
            float dre = wdre[n];
            float dim = gi - wlim[n];
            float den = fmaf(dim, dim, wdre2[n]);
            float inv = __builtin_amdgcn_rcpf(den);
            float rre = dre * inv;
            float rim = -dim * inv;
            float2 c00 = w00[n], c01 = w01[n], c10 = w10[n], c11 = w11[n];
            a00.x += c00.x * rre - c00.y * rim; a00.y += c00.x * rim + c00.y * rre;
            a01.x += c01.x * rre - c01.y * rim; a01.y += c01.x * rim + c01.y * rre;
            a10.x += c10.x * rre - c10.y * rim; a10.y += c10.x * rim + c10.y * rre;
            a11.x += c11.x * rre - c11.y * rim; a11.y += c11.x * rim + c11.y * rre;
        }
        float2 den1 = make_float2(1.0f + a11.x, a11.y);
        float inv = 1.0f / (den1.x * den1.x + den1.y * den1.y);
        float2 qn = cmul(a01, a10);
        float2 dv = make_float2((qn.x * den1.x + qn.y * den1.y) * inv,
                                (qn.y * den1.x - qn.x * den1.y) * inv);
        float2 tmp = make_float2(a00.x - dv.x, a00.y - dv.y);
        spec[SWZ(brev13(k))] = cmul(make_float2(1.0f, t), tmp);
    }
    __syncthreads();

    // ---- Hermitianize: reference drops imag(K), so spec <- (A + conj(mirror))/2 ----
    // (the /2 here also supplies one factor of the final (c+n)/2 split... no — it is
    //  the true spectrum of Re(K); the 0.5 for (c+n)/2 is applied at output.)
    if (type == 0) {
        for (int k = tid; k <= (L / 2); k += NTH) {
            int pa = SWZ(brev13(k));
            if (k == 0 || k == (L / 2)) {
                float2 v = spec[pa];
                spec[pa] = make_float2(v.x, 0.f);
            } else {
                int pb = SWZ(brev13(L - k));
                float2 va = spec[pa], vb = spec[pb];
                float2 Hv = make_float2(0.5f * (va.x + vb.x), 0.5f * (va.y - vb.y));
                spec[pa] = Hv;
                spec[pb] = make_float2(Hv.x, -Hv.y);
            }
        }
    } else {
        for (int k = tid; k < (L / 2); k += NTH) {
            int pa = SWZ(brev13(k));
            int pb = SWZ(brev13(L - 1 - k));
            float2 va = spec[pa], vb = spec[pb];
            float2 Hv = make_float2(0.5f * (va.x + vb.x), 0.5f * (va.y - vb.y));
            spec[pa] = Hv;
            spec[pb] = make_float2(Hv.x, -Hv.y);
        }
    }
    __syncthreads();

    // ---- forward FFT of (twisted) u ----
    fft_dif_single(bufA, tw, tid);

    // ---- pointwise multiply in bitrev domain (positions align) ----
    for (int i = tid; i < L; i += NTH) {
        int s = SWZ(i);
        bufA[s] = cmul(bufA[s], spec[s]);
    }
    __syncthreads();

    // ---- inverse FFT -> natural time order ----
    fft_dit_inv(bufA, tw, tid);

    // ---- output: y = 0.5*(c + n) + D*u, combined across the block pair ----
    const float sc = 0.5f / (float)L;   // 0.5 for (c+n)/2, 1/L for unscaled IFFT
    float* orow = out + (size_t)h * L;
    for (int t = tid; t < L; t += NTH) {
        float2 z = bufA[SWZ(t)];
        float val;
        if (type == 0) {
            val = z.x * sc + Dh * ur[t];
        } else {
            float2 w = twget<false>(tw, t >> 1);      // w[t] = e^{-i pi t/L}
            if (t & 1) w = cmul(w, W16K);
            // n[t] = Re(conj(w[t]) * z) = w.x*z.x + w.y*z.y  (w=(cos,-sin))
            val = (w.x * z.x + w.y * z.y) * sc;
        }
        atomicAdd(&orow[t], val);
    }
}

extern "C" void kernel_launch(void* const* d_in, const int* in_sizes, int n_in,
                              void* d_out, int out_size, void* d_ws, size_t ws_size,
                              hipStream_t stream) {
    (void)in_sizes; (void)n_in; (void)d_ws; (void)ws_size; (void)out_size;
    const float* u        = (const float*)d_in[0];
    const float* Ct_ri    = (const float*)d_in[1];
    const float* B_raw    = (const float*)d_in[2];
    const float* Dp       = (const float*)d_in[3];
    const float* log_step = (const float*)d_in[4];
    const float* Lre      = (const float*)d_in[5];
    const float* Lim      = (const float*)d_in[6];
    const float* p_re     = (const float*)d_in[7];
    const float* p_im     = (const float*)d_in[8];
    const float* q_re     = (const float*)d_in[9];
    const float* q_im     = (const float*)d_in[10];
    const float* Vc_re    = (const float*)d_in[11];
    const float* Vc_im    = (const float*)d_in[12];
    float* out = (float*)d_out;

    // zero the accumulation target (2 atomic addends per element -> deterministic)
    hipMemsetAsync(out, 0, (size_t)H * L * sizeof(float), stream);

    const size_t smem = (size_t)(2 * L + 2048 + 4 * NSTATE) * sizeof(float2)
                      + 3 * NSTATE * sizeof(float);
    hipFuncSetAttribute((const void*)s4_split_kernel,
                        hipFuncAttributeMaxDynamicSharedMemorySize, (int)smem);
    s4_split_kernel<<<dim3(2 * H), dim3(NTH), smem, stream>>>(
        u, Ct_ri, B_raw, Dp, log_step, Lre, Lim,
        p_re, p_im, q_re, q_im, Vc_re, Vc_im, out);
}

// Round 4
// 103.843 us; speedup vs baseline: 2.6527x; 1.5311x over previous
//
#include <hip/hip_runtime.h>
#include <math.h>

#define H 128
#define L 8192
#define NSTATE 64
#define NTH 1024
#define LPT (L / NTH)
#define PI_D 3.14159265358979323846
#define RT2 0.70710678118654752440f

// e^{-i*pi/8192}
#define W16K_RE 0.99999992646571789f
#define W16K_IM (-3.8349518757139556e-4f)
// e^{-i*pi/16384}
#define W32K_RE 0.99999998161642898f
#define W32K_IM (-1.9174759731070332e-4f)

__device__ __forceinline__ int SWZ(int e) { return e ^ ((e >> 3) & 7); }
__device__ __forceinline__ int TSW(int j) { return j ^ ((j >> 4) & 15) ^ ((j >> 8) & 15); }
__device__ __forceinline__ int brev13(int x) { return (int)(__brev((unsigned)x) >> 19); }

__device__ __forceinline__ float2 cmul(float2 a, float2 b) {
    return make_float2(a.x * b.x - a.y * b.y, a.x * b.y + a.y * b.x);
}
__device__ __forceinline__ float2 cadd(float2 a, float2 b) { return make_float2(a.x + b.x, a.y + b.y); }
__device__ __forceinline__ float2 csub(float2 a, float2 b) { return make_float2(a.x - b.x, a.y - b.y); }
__device__ __forceinline__ float2 mnegi(float2 a) { return make_float2(a.y, -a.x); }  // a * (-i)
__device__ __forceinline__ float2 mposi(float2 a) { return make_float2(-a.y, a.x); }  // a * (+i)

// W_8192^idx for idx in [0,4096); INV -> conjugate
template<bool INV>
__device__ __forceinline__ float2 twget(const float2* __restrict__ tw, int idx) {
    float2 w;
    if (idx < 2048) w = tw[TSW(idx)];
    else { float2 t = tw[TSW(idx - 2048)]; w = make_float2(t.y, -t.x); }  // * (-i)
    if (INV) w.y = -w.y;
    return w;
}

// ---- forward DIF fused pair (stage sizes 4*SIGMA then 2*SIGMA) ----
template<int SIGMA>
__device__ __forceinline__ void dif_pass1(float2* __restrict__ A,
                                          const float2* __restrict__ tw, int tid) {
    const int m1 = 2048 / SIGMA;
    #pragma unroll
    for (int rep = 0; rep < 2; ++rep) {
        int q = tid + rep * NTH;
        int r = q & (SIGMA - 1);
        int b = ((q & ~(SIGMA - 1)) << 2) | r;
        float2 w1 = twget<false>(tw, r * m1);        // W_{4s}^r
        float2 w2 = twget<false>(tw, 2 * r * m1);    // W_{2s}^r
        float2 w1b = mnegi(w1);                      // W_{4s}^{r+s}
        int i0 = SWZ(b), i1 = SWZ(b + SIGMA), i2 = SWZ(b + 2 * SIGMA), i3 = SWZ(b + 3 * SIGMA);
        float2 x0 = A[i0], x1 = A[i1], x2 = A[i2], x3 = A[i3];
        float2 y0 = cadd(x0, x2), y2 = cmul(csub(x0, x2), w1);
        float2 y1 = cadd(x1, x3), y3 = cmul(csub(x1, x3), w1b);
        A[i0] = cadd(y0, y1); A[i1] = cmul(csub(y0, y1), w2);
        A[i2] = cadd(y2, y3); A[i3] = cmul(csub(y2, y3), w2);
    }
}

// ---- forward DIF radix-8 final pass (stage sizes 8,4,2), one 8-block ----
__device__ __forceinline__ void dif_r8_one(float2* __restrict__ A, int base) {
    float2 x0 = A[SWZ(base + 0)], x1 = A[SWZ(base + 1)], x2 = A[SWZ(base + 2)], x3 = A[SWZ(base + 3)];
    float2 x4 = A[SWZ(base + 4)], x5 = A[SWZ(base + 5)], x6 = A[SWZ(base + 6)], x7 = A[SWZ(base + 7)];
    float2 a0 = cadd(x0, x4), a1 = cadd(x1, x5), a2 = cadd(x2, x6), a3 = cadd(x3, x7);
    float2 s0 = csub(x0, x4), s1 = csub(x1, x5), s2 = csub(x2, x6), s3 = csub(x3, x7);
    float2 b0 = s0;
    float2 b1 = cmul(s1, make_float2(RT2, -RT2));
    float2 b2 = mnegi(s2);
    float2 b3 = cmul(s3, make_float2(-RT2, -RT2));
    float2 c0 = cadd(a0, a2), c2 = csub(a0, a2);
    float2 c1 = cadd(a1, a3), c3 = mnegi(csub(a1, a3));
    float2 d0 = cadd(b0, b2), d2 = csub(b0, b2);
    float2 d1 = cadd(b1, b3), d3 = mnegi(csub(b1, b3));
    A[SWZ(base + 0)] = cadd(c0, c1); A[SWZ(base + 1)] = csub(c0, c1);
    A[SWZ(base + 2)] = cadd(c2, c3); A[SWZ(base + 3)] = csub(c2, c3);
    A[SWZ(base + 4)] = cadd(d0, d1); A[SWZ(base + 5)] = csub(d0, d1);
    A[SWZ(base + 6)] = cadd(d2, d3); A[SWZ(base + 7)] = csub(d2, d3);
}

// ---- inverse DIT radix-8 first pass (stage sizes 2,4,8), one 8-block ----
__device__ __forceinline__ void dit_r8_one(float2* __restrict__ A, int base) {
    float2 x0 = A[SWZ(base + 0)], x1 = A[SWZ(base + 1)], x2 = A[SWZ(base + 2)], x3 = A[SWZ(base + 3)];
    float2 x4 = A[SWZ(base + 4)], x5 = A[SWZ(base + 5)], x6 = A[SWZ(base + 6)], x7 = A[SWZ(base + 7)];
    float2 a0 = cadd(x0, x1), a1 = csub(x0, x1), a2 = cadd(x2, x3), a3 = csub(x2, x3);
    float2 a4 = cadd(x4, x5), a5 = csub(x4, x5), a6 = cadd(x6, x7), a7 = csub(x6, x7);
    float2 b0 = cadd(a0, a2), b2 = csub(a0, a2);
    float2 t13 = mposi(a3); float2 b1 = cadd(a1, t13), b3 = csub(a1, t13);
    float2 b4 = cadd(a4, a6), b6 = csub(a4, a6);
    float2 t57 = mposi(a7); float2 b5 = cadd(a5, t57), b7 = csub(a5, t57);
    float2 t4 = b4;
    float2 t5 = cmul(make_float2(RT2, RT2), b5);
    float2 t6 = mposi(b6);
    float2 t7 = cmul(make_float2(-RT2, RT2), b7);
    A[SWZ(base + 0)] = cadd(b0, t4); A[SWZ(base + 4)] = csub(b0, t4);
    A[SWZ(base + 1)] = cadd(b1, t5); A[SWZ(base + 5)] = csub(b1, t5);
    A[SWZ(base + 2)] = cadd(b2, t6); A[SWZ(base + 6)] = csub(b2, t6);
    A[SWZ(base + 3)] = cadd(b3, t7); A[SWZ(base + 7)] = csub(b3, t7);
}

// ---- inverse DIT fused pair (stage halves SIGMA then 2*SIGMA) ----
template<int SIGMA>
__device__ __forceinline__ void dit_pass1(float2* __restrict__ A,
                                          const float2* __restrict__ tw, int tid) {
    const int m1 = 2048 / SIGMA;
    #pragma unroll
    for (int rep = 0; rep < 2; ++rep) {
        int q = tid + rep * NTH;
        int r = q & (SIGMA - 1);
        int b = ((q & ~(SIGMA - 1)) << 2) | r;
        float2 w1 = twget<true>(tw, 2 * r * m1);     // conj W_{2s}^r
        float2 w2 = twget<true>(tw, r * m1);         // conj W_{4s}^r
        float2 w2b = mposi(w2);                      // conj W_{4s}^{r+s}
        int i0 = SWZ(b), i1 = SWZ(b + SIGMA), i2 = SWZ(b + 2 * SIGMA), i3 = SWZ(b + 3 * SIGMA);
        float2 x0 = A[i0], x1 = A[i1], x2 = A[i2], x3 = A[i3];
        float2 t1 = cmul(w1, x1);
        float2 y0 = cadd(x0, t1), y1 = csub(x0, t1);
        float2 t3 = cmul(w1, x3);
        float2 y2 = cadd(x2, t3), y3 = csub(x2, t3);
        float2 u2 = cmul(w2, y2);
        A[i0] = cadd(y0, u2); A[i2] = csub(y0, u2);
        float2 u3 = cmul(w2b, y3);
        A[i1] = cadd(y1, u3); A[i3] = csub(y1, u3);
    }
}

// inverse FFT: bit-reversed input -> natural output (unscaled)
__device__ __forceinline__ void fft_dit_inv(float2* __restrict__ A,
                                            const float2* __restrict__ tw, int tid) {
    dit_r8_one(A, tid * 8);      __syncthreads();
    dit_pass1<8>(A, tw, tid);    __syncthreads();
    dit_pass1<32>(A, tw, tid);   __syncthreads();
    dit_pass1<128>(A, tw, tid);  __syncthreads();
    dit_pass1<512>(A, tw, tid);  __syncthreads();
    dit_pass1<2048>(A, tw, tid); __syncthreads();
}

// forward FFT: natural input -> bit-reversed output
__device__ __forceinline__ void fft_dif_single(float2* __restrict__ A,
                                               const float2* __restrict__ tw, int tid) {
    dif_pass1<2048>(A, tw, tid); __syncthreads();
    dif_pass1<512>(A, tw, tid);  __syncthreads();
    dif_pass1<128>(A, tw, tid);  __syncthreads();
    dif_pass1<32>(A, tw, tid);   __syncthreads();
    dif_pass1<8>(A, tw, tid);    __syncthreads();
    dif_r8_one(A, tid * 8);      __syncthreads();
}

extern __shared__ char smem_raw[];

// Grid = 256: blocks 0..127 cyclic part (type 0), 128..255 negacyclic (type 1).
// y = 0.5*(cyclic + negacyclic) + D*u, combined via atomicAdd on zeroed out.
__global__ __launch_bounds__(NTH)
void s4_split_kernel(const float* __restrict__ u,
                     const float* __restrict__ Ct_ri,
                     const float* __restrict__ B_raw,
                     const float* __restrict__ Dp,
                     const float* __restrict__ log_step,
                     const float* __restrict__ Lre_g,
                     const float* __restrict__ Lim_g,
                     const float* __restrict__ p_re,
                     const float* __restrict__ p_im,
                     const float* __restrict__ q_re,
                     const float* __restrict__ q_im,
                     const float* __restrict__ Vc_re,
                     const float* __restrict__ Vc_im,
                     float* __restrict__ out)
{
    float2* bufA = (float2*)smem_raw;          // 8192 complex (swizzled)
    float2* spec = bufA + L;                   // 8192 complex (swizzled, bitrev domain)
    float2* tw   = spec + L;                   // 2048 complex twiddles (swizzled)
    float4* wq4  = (float4*)(tw + 2048);       // 64: (w00.x,w00.y,w01.x,w01.y)
    float4* wr4  = wq4 + NSTATE;               // 64: (w10.x,w10.y,w11.x,w11.y)
    float4* wp4  = wr4 + NSTATE;               // 64: (dre, dre^2, lim, 0)

    const int bid  = blockIdx.x;
    const int type = bid >> 7;          // 0 = cyclic, 1 = negacyclic
    const int h    = bid & (H - 1);
    const int tid  = threadIdx.x;

    // ---- setup: twiddle table (double-precision angles, once) ----
    for (int j = tid; j < 2048; j += NTH) {
        double a = -2.0 * PI_D * (double)j / (double)L;
        tw[TSW(j)] = make_float2((float)cos(a), (float)sin(a));
    }
    // ---- setup: per-channel Cauchy weights (packed float4) ----
    if (tid < NSTATE) {
        int n = tid;
        float2 Bc = make_float2(0.f, 0.f);
        for (int m = 0; m < NSTATE; ++m) {
            float br = B_raw[h * NSTATE + m];
            Bc.x += Vc_re[n * NSTATE + m] * br;
            Bc.y += Vc_im[n * NSTATE + m] * br;
        }
        float2 Ctc = make_float2(Ct_ri[(h * NSTATE + n) * 2 + 0],
                                 -Ct_ri[(h * NSTATE + n) * 2 + 1]);
        float2 pc = make_float2(p_re[n], p_im[n]);
        float2 qc = make_float2(q_re[n], -q_im[n]);
        float2 w00 = cmul(Ctc, Bc);
        float2 w01 = cmul(Ctc, pc);
        float2 w10 = cmul(qc, Bc);
        float2 w11 = cmul(qc, pc);
        float dre = -Lre_g[n];
        wq4[n] = make_float4(w00.x, w00.y, w01.x, w01.y);
        wr4[n] = make_float4(w10.x, w10.y, w11.x, w11.y);
        wp4[n] = make_float4(dre, dre * dre, Lim_g[n], 0.f);
    }
    __syncthreads();

    const float step = expf(log_step[h]);
    const float two_over_step = 2.0f / step;
    const float Dh = Dp[h];
    const float* ur = u + (size_t)h * L;
    const float2 W16K = make_float2(W16K_RE, W16K_IM);
    const float2 W32K = make_float2(W32K_RE, W32K_IM);

    // ---- load u (type1: twisted by w[t]=e^{-i pi t/L}) into bufA, natural order ----
    for (int i = tid; i < L; i += NTH) {
        float uv = ur[i];
        if (type == 0) {
            bufA[SWZ(i)] = make_float2(uv, 0.f);
        } else {
            float2 w = twget<false>(tw, i >> 1);
            if (i & 1) w = cmul(w, W16K);
            bufA[SWZ(i)] = make_float2(uv * w.x, uv * w.y);
        }
    }

    // ---- Cauchy: transfer fn at freq k (+0.5 for type1), deposit bitrev ----
    // t = tan(pi*(k+off)/L) from table: e^{-i pi k / L} = tw[k>>1] * (k&1 ? W16K : 1),
    //  half-offset adds W32K. t = sin/cos = -w.y * rcp(w.x). Worst-case rel err ~3e-4
    //  near k=4096 where at_roots sensitivity is O(1/t^2) -> negligible.
    #pragma unroll
    for (int chunk = 0; chunk < 2; ++chunk) {
        float tv[4], gv[4];
        #pragma unroll
        for (int j4 = 0; j4 < 4; ++j4) {
            int k = tid + (chunk * 4 + j4) * NTH;
            float2 w = twget<false>(tw, k >> 1);
            if (k & 1) w = cmul(w, W16K);
            if (type)  w = cmul(w, W32K);
            float t = -w.y * __builtin_amdgcn_rcpf(w.x);
            t = fminf(fmaxf(t, -3.0e7f), 3.0e7f);
            tv[j4] = t;
            gv[j4] = two_over_step * t;
        }
        float2 A00[4], A01[4], A10[4], A11[4];
        #pragma unroll
        for (int j4 = 0; j4 < 4; ++j4) {
            A00[j4] = make_float2(0.f, 0.f); A01[j4] = make_float2(0.f, 0.f);
            A10[j4] = make_float2(0.f, 0.f); A11[j4] = make_float2(0.f, 0.f);
        }
        #pragma unroll 2
        for (int n = 0; n < NSTATE; ++n) {
            float4 qv = wq4[n];   // w00, w01
            float4 rv = wr4[n];   // w10, w11
            float4 pv = wp4[n];   // dre, dre^2, lim
            #pragma unroll
            for (int j4 = 0; j4 < 4; ++j4) {
                float dim = gv[j4] - pv.z;
                float den = fmaf(dim, dim, pv.y);
                float inv = __builtin_amdgcn_rcpf(den);
                float rre = pv.x * inv;
                float rim = -dim * inv;
                A00[j4].x = fmaf(qv.x, rre, fmaf(-qv.y, rim, A00[j4].x));
                A00[j4].y = fmaf(qv.x, rim, fmaf( qv.y, rre, A00[j4].y));
                A01[j4].x = fmaf(qv.z, rre, fmaf(-qv.w, rim, A01[j4].x));
                A01[j4].y = fmaf(qv.z, rim, fmaf( qv.w, rre, A01[j4].y));
                A10[j4].x = fmaf(rv.x, rre, fmaf(-rv.y, rim, A10[j4].x));
                A10[j4].y = fmaf(rv.x, rim, fmaf( rv.y, rre, A10[j4].y));
                A11[j4].x = fmaf(rv.z, rre, fmaf(-rv.w, rim, A11[j4].x));
                A11[j4].y = fmaf(rv.z, rim, fmaf( rv.w, rre, A11[j4].y));
            }
        }
        #pragma unroll
        for (int j4 = 0; j4 < 4; ++j4) {
            int k = tid + (chunk * 4 + j4) * NTH;
            float2 den1 = make_float2(1.0f + A11[j4].x, A11[j4].y);
            float inv = 1.0f / (den1.x * den1.x + den1.y * den1.y);
            float2 qn = cmul(A01[j4], A10[j4]);
            float2 dv = make_float2((qn.x * den1.x + qn.y * den1.y) * inv,
                                    (qn.y * den1.x - qn.x * den1.y) * inv);
            float2 tmp = make_float2(A00[j4].x - dv.x, A00[j4].y - dv.y);
            spec[SWZ(brev13(k))] = cmul(make_float2(1.0f, tv[j4]), tmp);
        }
    }
    __syncthreads();

    // ---- Hermitianize: reference drops imag(K) -> spec <- (A + conj(mirror))/2 ----
    if (type == 0) {
        for (int k = tid; k <= (L / 2); k += NTH) {
            int pa = SWZ(brev13(k));
            if (k == 0 || k == (L / 2)) {
                float2 v = spec[pa];
                spec[pa] = make_float2(v.x, 0.f);
            } else {
                int pb = SWZ(brev13(L - k));
                float2 va = spec[pa], vb = spec[pb];
                float2 Hv = make_float2(0.5f * (va.x + vb.x), 0.5f * (va.y - vb.y));
                spec[pa] = Hv;
                spec[pb] = make_float2(Hv.x, -Hv.y);
            }
        }
    } else {
        for (int k = tid; k < (L / 2); k += NTH) {
            int pa = SWZ(brev13(k));
            int pb = SWZ(brev13(L - 1 - k));
            float2 va = spec[pa], vb = spec[pb];
            float2 Hv = make_float2(0.5f * (va.x + vb.x), 0.5f * (va.y - vb.y));
            spec[pa] = Hv;
            spec[pb] = make_float2(Hv.x, -Hv.y);
        }
    }
    __syncthreads();

    // ---- forward FFT of (twisted) u ----
    fft_dif_single(bufA, tw, tid);

    // ---- pointwise multiply in bitrev domain (positions align) ----
    for (int i = tid; i < L; i += NTH) {
        int s = SWZ(i);
        bufA[s] = cmul(bufA[s], spec[s]);
    }
    __syncthreads();

    // ---- inverse FFT -> natural time order ----
    fft_dit_inv(bufA, tw, tid);

    // ---- output: y = 0.5*(c + n) + D*u, combined across the block pair ----
    const float sc = 0.5f / (float)L;   // 0.5 for (c+n)/2, 1/L for unscaled IFFT
    float* orow = out + (size_t)h * L;
    for (int t = tid; t < L; t += NTH) {
        float2 z = bufA[SWZ(t)];
        float val;
        if (type == 0) {
            val = z.x * sc + Dh * ur[t];
        } else {
            float2 w = twget<false>(tw, t >> 1);      // w[t] = e^{-i pi t/L}
            if (t & 1) w = cmul(w, W16K);
            // n[t] = Re(conj(w[t]) * z) = w.x*z.x + w.y*z.y
            val = (w.x * z.x + w.y * z.y) * sc;
        }
        atomicAdd(&orow[t], val);
    }
}

extern "C" void kernel_launch(void* const* d_in, const int* in_sizes, int n_in,
                              void* d_out, int out_size, void* d_ws, size_t ws_size,
                              hipStream_t stream) {
    (void)in_sizes; (void)n_in; (void)d_ws; (void)ws_size; (void)out_size;
    const float* u        = (const float*)d_in[0];
    const float* Ct_ri    = (const float*)d_in[1];
    const float* B_raw    = (const float*)d_in[2];
    const float* Dp       = (const float*)d_in[3];
    const float* log_step = (const float*)d_in[4];
    const float* Lre      = (const float*)d_in[5];
    const float* Lim      = (const float*)d_in[6];
    const float* p_re     = (const float*)d_in[7];
    const float* p_im     = (const float*)d_in[8];
    const float* q_re     = (const float*)d_in[9];
    const float* q_im     = (const float*)d_in[10];
    const float* Vc_re    = (const float*)d_in[11];
    const float* Vc_im    = (const float*)d_in[12];
    float* out = (float*)d_out;

    // zero the accumulation target (2 atomic addends per element -> deterministic)
    hipMemsetAsync(out, 0, (size_t)H * L * sizeof(float), stream);

    const size_t smem = (size_t)(2 * L + 2048) * sizeof(float2)
                      + 3 * NSTATE * sizeof(float4);
    hipFuncSetAttribute((const void*)s4_split_kernel,
                        hipFuncAttributeMaxDynamicSharedMemorySize, (int)smem);
    s4_split_kernel<<<dim3(2 * H), dim3(NTH), smem, stream>>>(
        u, Ct_ri, B_raw, Dp, log_step, Lre, Lim,
        p_re, p_im, q_re, q_im, Vc_re, Vc_im, out);
}

// Round 5
// 102.356 us; speedup vs baseline: 2.6912x; 1.0145x over previous
//
#include <hip/hip_runtime.h>
#include <math.h>

#define H 128
#define L 8192
#define NSTATE 64
#define NTH 1024
#define LPT (L / NTH)
#define PI_D 3.14159265358979323846
#define RT2 0.70710678118654752440f

// e^{-i*pi/8192}
#define W16K_RE 0.99999992646571789f
#define W16K_IM (-3.8349518757139556e-4f)
// e^{-i*pi/16384}
#define W32K_RE 0.99999998161642898f
#define W32K_IM (-1.9174759731070332e-4f)

__device__ __forceinline__ int SWZ(int e) { return e ^ ((e >> 3) & 7); }
__device__ __forceinline__ int TSW(int j) { return j ^ ((j >> 4) & 15) ^ ((j >> 8) & 15); }
__device__ __forceinline__ int brev13(int x) { return (int)(__brev((unsigned)x) >> 19); }

__device__ __forceinline__ float2 cmul(float2 a, float2 b) {
    return make_float2(a.x * b.x - a.y * b.y, a.x * b.y + a.y * b.x);
}
__device__ __forceinline__ float2 cadd(float2 a, float2 b) { return make_float2(a.x + b.x, a.y + b.y); }
__device__ __forceinline__ float2 csub(float2 a, float2 b) { return make_float2(a.x - b.x, a.y - b.y); }
__device__ __forceinline__ float2 mnegi(float2 a) { return make_float2(a.y, -a.x); }  // a * (-i)
__device__ __forceinline__ float2 mposi(float2 a) { return make_float2(-a.y, a.x); }  // a * (+i)

// W_8192^idx for idx in [0,4096); INV -> conjugate
template<bool INV>
__device__ __forceinline__ float2 twget(const float2* __restrict__ tw, int idx) {
    float2 w;
    if (idx < 2048) w = tw[TSW(idx)];
    else { float2 t = tw[TSW(idx - 2048)]; w = make_float2(t.y, -t.x); }  // * (-i)
    if (INV) w.y = -w.y;
    return w;
}

// ---- forward DIF fused pair (stage sizes 4*SIGMA then 2*SIGMA) ----
template<int SIGMA>
__device__ __forceinline__ void dif_pass1(float2* __restrict__ A,
                                          const float2* __restrict__ tw, int tid) {
    const int m1 = 2048 / SIGMA;
    #pragma unroll
    for (int rep = 0; rep < 2; ++rep) {
        int q = tid + rep * NTH;
        int r = q & (SIGMA - 1);
        int b = ((q & ~(SIGMA - 1)) << 2) | r;
        float2 w1 = twget<false>(tw, r * m1);        // W_{4s}^r
        float2 w2 = twget<false>(tw, 2 * r * m1);    // W_{2s}^r
        float2 w1b = mnegi(w1);                      // W_{4s}^{r+s}
        int i0 = SWZ(b), i1 = SWZ(b + SIGMA), i2 = SWZ(b + 2 * SIGMA), i3 = SWZ(b + 3 * SIGMA);
        float2 x0 = A[i0], x1 = A[i1], x2 = A[i2], x3 = A[i3];
        float2 y0 = cadd(x0, x2), y2 = cmul(csub(x0, x2), w1);
        float2 y1 = cadd(x1, x3), y3 = cmul(csub(x1, x3), w1b);
        A[i0] = cadd(y0, y1); A[i1] = cmul(csub(y0, y1), w2);
        A[i2] = cadd(y2, y3); A[i3] = cmul(csub(y2, y3), w2);
    }
}

// ---- inverse DIT fused pair (stage halves SIGMA then 2*SIGMA) ----
template<int SIGMA>
__device__ __forceinline__ void dit_pass1(float2* __restrict__ A,
                                          const float2* __restrict__ tw, int tid) {
    const int m1 = 2048 / SIGMA;
    #pragma unroll
    for (int rep = 0; rep < 2; ++rep) {
        int q = tid + rep * NTH;
        int r = q & (SIGMA - 1);
        int b = ((q & ~(SIGMA - 1)) << 2) | r;
        float2 w1 = twget<true>(tw, 2 * r * m1);     // conj W_{2s}^r
        float2 w2 = twget<true>(tw, r * m1);         // conj W_{4s}^r
        float2 w2b = mposi(w2);                      // conj W_{4s}^{r+s}
        int i0 = SWZ(b), i1 = SWZ(b + SIGMA), i2 = SWZ(b + 2 * SIGMA), i3 = SWZ(b + 3 * SIGMA);
        float2 x0 = A[i0], x1 = A[i1], x2 = A[i2], x3 = A[i3];
        float2 t1 = cmul(w1, x1);
        float2 y0 = cadd(x0, t1), y1 = csub(x0, t1);
        float2 t3 = cmul(w1, x3);
        float2 y2 = cadd(x2, t3), y3 = csub(x2, t3);
        float2 u2 = cmul(w2, y2);
        A[i0] = cadd(y0, u2); A[i2] = csub(y0, u2);
        float2 u3 = cmul(w2b, y3);
        A[i1] = cadd(y1, u3); A[i3] = csub(y1, u3);
    }
}

extern __shared__ char smem_raw[];

// Grid = 256: blocks 0..127 cyclic part (type 0), 128..255 negacyclic (type 1).
// y = 0.5*(cyclic + negacyclic) + D*u, combined via atomicAdd on zeroed out.
// Hermitianization of the kernel spectrum is provably redundant (u real =>
// U (type0) / twisted-U (type1) already carry the conjugate symmetry; final
// Re() drops the anti-symmetric part exactly).
__global__ __launch_bounds__(NTH, 4)
void s4_split_kernel(const float* __restrict__ u,
                     const float* __restrict__ Ct_ri,
                     const float* __restrict__ B_raw,
                     const float* __restrict__ Dp,
                     const float* __restrict__ log_step,
                     const float* __restrict__ Lre_g,
                     const float* __restrict__ Lim_g,
                     const float* __restrict__ p_re,
                     const float* __restrict__ p_im,
                     const float* __restrict__ q_re,
                     const float* __restrict__ q_im,
                     const float* __restrict__ Vc_re,
                     const float* __restrict__ Vc_im,
                     float* __restrict__ out)
{
    float2* bufA = (float2*)smem_raw;          // 8192 complex (swizzled)
    float2* tw   = bufA + L;                   // 2048 complex twiddles (swizzled)
    float4* wq4  = (float4*)(tw + 2048);       // 64: (w00.x,w00.y,w01.x,w01.y)
    float4* wr4  = wq4 + NSTATE;               // 64: (w10.x,w10.y,w11.x,w11.y)
    float4* wp4  = wr4 + NSTATE;               // 64: (dre, dre^2, lim, 0)

    const int bid  = blockIdx.x;
    const int type = bid >> 7;          // 0 = cyclic, 1 = negacyclic
    const int h    = bid & (H - 1);
    const int tid  = threadIdx.x;

    // ---- setup: twiddle table (double-precision angles, once) ----
    for (int j = tid; j < 2048; j += NTH) {
        double a = -2.0 * PI_D * (double)j / (double)L;
        tw[TSW(j)] = make_float2((float)cos(a), (float)sin(a));
    }
    // ---- setup: per-channel Cauchy weights (packed float4) ----
    if (tid < NSTATE) {
        int n = tid;
        float2 Bc = make_float2(0.f, 0.f);
        for (int m = 0; m < NSTATE; ++m) {
            float br = B_raw[h * NSTATE + m];
            Bc.x += Vc_re[n * NSTATE + m] * br;
            Bc.y += Vc_im[n * NSTATE + m] * br;
        }
        float2 Ctc = make_float2(Ct_ri[(h * NSTATE + n) * 2 + 0],
                                 -Ct_ri[(h * NSTATE + n) * 2 + 1]);
        float2 pc = make_float2(p_re[n], p_im[n]);
        float2 qc = make_float2(q_re[n], -q_im[n]);
        float2 w00 = cmul(Ctc, Bc);
        float2 w01 = cmul(Ctc, pc);
        float2 w10 = cmul(qc, Bc);
        float2 w11 = cmul(qc, pc);
        float dre = -Lre_g[n];
        wq4[n] = make_float4(w00.x, w00.y, w01.x, w01.y);
        wr4[n] = make_float4(w10.x, w10.y, w11.x, w11.y);
        wp4[n] = make_float4(dre, dre * dre, Lim_g[n], 0.f);
    }
    __syncthreads();

    const float step = expf(log_step[h]);
    const float two_over_step = 2.0f / step;
    const float Dh = Dp[h];
    const float* ur = u + (size_t)h * L;
    const float2 W16K = make_float2(W16K_RE, W16K_IM);
    const float2 W32K = make_float2(W32K_RE, W32K_IM);

    // ---- load u (type1: twisted by w[t]=e^{-i pi t/L}) into bufA, natural order ----
    for (int i = tid; i < L; i += NTH) {
        float uv = ur[i];
        if (type == 0) {
            bufA[SWZ(i)] = make_float2(uv, 0.f);
        } else {
            float2 w = twget<false>(tw, i >> 1);
            if (i & 1) w = cmul(w, W16K);
            bufA[SWZ(i)] = make_float2(uv * w.x, uv * w.y);
        }
    }

    // ---- Cauchy: transfer fn for freqs k_j = brev13(8*tid+j), kept in REGISTERS ----
    // (position 8*tid+j of the bitrev-ordered forward-FFT output holds freq brev13(8*tid+j),
    //  so these are exactly the values this thread needs at the FFT seam.)
    float2 spec[8];
    #pragma unroll
    for (int chunk = 0; chunk < 2; ++chunk) {
        float tv[4], gv[4];
        #pragma unroll
        for (int j4 = 0; j4 < 4; ++j4) {
            int k = brev13(8 * tid + chunk * 4 + j4);
            float2 w = twget<false>(tw, k >> 1);
            float2 wo = cmul(w, W16K);
            if (k & 1) w = wo;            // wave-uniform (k&1 = bit12 of 8*tid+j)
            if (type)  w = cmul(w, W32K);
            float t = -w.y * __builtin_amdgcn_rcpf(w.x);
            t = fminf(fmaxf(t, -3.0e7f), 3.0e7f);
            tv[j4] = t;
            gv[j4] = two_over_step * t;
        }
        float2 A00[4], A01[4], A10[4], A11[4];
        #pragma unroll
        for (int j4 = 0; j4 < 4; ++j4) {
            A00[j4] = make_float2(0.f, 0.f); A01[j4] = make_float2(0.f, 0.f);
            A10[j4] = make_float2(0.f, 0.f); A11[j4] = make_float2(0.f, 0.f);
        }
        #pragma unroll 2
        for (int n = 0; n < NSTATE; ++n) {
            float4 qv = wq4[n];   // w00, w01
            float4 rv = wr4[n];   // w10, w11
            float4 pv = wp4[n];   // dre, dre^2, lim
            #pragma unroll
            for (int j4 = 0; j4 < 4; ++j4) {
                float dim = gv[j4] - pv.z;
                float den = fmaf(dim, dim, pv.y);
                float inv = __builtin_amdgcn_rcpf(den);
                float rre = pv.x * inv;
                float rim = -dim * inv;
                A00[j4].x = fmaf(qv.x, rre, fmaf(-qv.y, rim, A00[j4].x));
                A00[j4].y = fmaf(qv.x, rim, fmaf( qv.y, rre, A00[j4].y));
                A01[j4].x = fmaf(qv.z, rre, fmaf(-qv.w, rim, A01[j4].x));
                A01[j4].y = fmaf(qv.z, rim, fmaf( qv.w, rre, A01[j4].y));
                A10[j4].x = fmaf(rv.x, rre, fmaf(-rv.y, rim, A10[j4].x));
                A10[j4].y = fmaf(rv.x, rim, fmaf( rv.y, rre, A10[j4].y));
                A11[j4].x = fmaf(rv.z, rre, fmaf(-rv.w, rim, A11[j4].x));
                A11[j4].y = fmaf(rv.z, rim, fmaf( rv.w, rre, A11[j4].y));
            }
        }
        #pragma unroll
        for (int j4 = 0; j4 < 4; ++j4) {
            float2 den1 = make_float2(1.0f + A11[j4].x, A11[j4].y);
            float inv = 1.0f / (den1.x * den1.x + den1.y * den1.y);
            float2 qn = cmul(A01[j4], A10[j4]);
            float2 dv = make_float2((qn.x * den1.x + qn.y * den1.y) * inv,
                                    (qn.y * den1.x - qn.x * den1.y) * inv);
            float2 tmp = make_float2(A00[j4].x - dv.x, A00[j4].y - dv.y);
            spec[chunk * 4 + j4] = cmul(make_float2(1.0f, tv[j4]), tmp);
        }
    }
    __syncthreads();   // bufA (u) now visible to all

    // ---- forward DIF passes (stages 13..4) ----
    dif_pass1<2048>(bufA, tw, tid); __syncthreads();
    dif_pass1<512>(bufA, tw, tid);  __syncthreads();
    dif_pass1<128>(bufA, tw, tid);  __syncthreads();
    dif_pass1<32>(bufA, tw, tid);   __syncthreads();
    dif_pass1<8>(bufA, tw, tid);    __syncthreads();

    // ---- fused seam: DIF radix-8 -> ×spec -> DIT radix-8, all in registers ----
    {
        const int base = tid * 8;
        float2 x0 = bufA[SWZ(base + 0)], x1 = bufA[SWZ(base + 1)];
        float2 x2 = bufA[SWZ(base + 2)], x3 = bufA[SWZ(base + 3)];
        float2 x4 = bufA[SWZ(base + 4)], x5 = bufA[SWZ(base + 5)];
        float2 x6 = bufA[SWZ(base + 6)], x7 = bufA[SWZ(base + 7)];
        // DIF radix-8 (stages 8,4,2)
        float2 a0 = cadd(x0, x4), a1 = cadd(x1, x5), a2 = cadd(x2, x6), a3 = cadd(x3, x7);
        float2 s0 = csub(x0, x4), s1 = csub(x1, x5), s2 = csub(x2, x6), s3 = csub(x3, x7);
        float2 b0 = s0;
        float2 b1 = cmul(s1, make_float2(RT2, -RT2));
        float2 b2 = mnegi(s2);
        float2 b3 = cmul(s3, make_float2(-RT2, -RT2));
        float2 c0 = cadd(a0, a2), c2 = csub(a0, a2);
        float2 c1 = cadd(a1, a3), c3 = mnegi(csub(a1, a3));
        float2 d0 = cadd(b0, b2), d2 = csub(b0, b2);
        float2 d1 = cadd(b1, b3), d3 = mnegi(csub(b1, b3));
        float2 y0 = cadd(c0, c1), y1 = csub(c0, c1);
        float2 y2 = cadd(c2, c3), y3 = csub(c2, c3);
        float2 y4 = cadd(d0, d1), y5 = csub(d0, d1);
        float2 y6 = cadd(d2, d3), y7 = csub(d2, d3);
        // pointwise multiply by the Cauchy spectrum (register-resident)
        y0 = cmul(y0, spec[0]); y1 = cmul(y1, spec[1]);
        y2 = cmul(y2, spec[2]); y3 = cmul(y3, spec[3]);
        y4 = cmul(y4, spec[4]); y5 = cmul(y5, spec[5]);
        y6 = cmul(y6, spec[6]); y7 = cmul(y7, spec[7]);
        // DIT radix-8 (stages 2,4,8)
        float2 e0 = cadd(y0, y1), e1 = csub(y0, y1), e2 = cadd(y2, y3), e3 = csub(y2, y3);
        float2 e4 = cadd(y4, y5), e5 = csub(y4, y5), e6 = cadd(y6, y7), e7 = csub(y6, y7);
        float2 f0 = cadd(e0, e2), f2 = csub(e0, e2);
        float2 ti = mposi(e3); float2 f1 = cadd(e1, ti), f3 = csub(e1, ti);
        float2 f4 = cadd(e4, e6), f6 = csub(e4, e6);
        float2 tj = mposi(e7); float2 f5 = cadd(e5, tj), f7 = csub(e5, tj);
        float2 g4 = f4;
        float2 g5 = cmul(make_float2(RT2, RT2), f5);
        float2 g6 = mposi(f6);
        float2 g7 = cmul(make_float2(-RT2, RT2), f7);
        bufA[SWZ(base + 0)] = cadd(f0, g4); bufA[SWZ(base + 4)] = csub(f0, g4);
        bufA[SWZ(base + 1)] = cadd(f1, g5); bufA[SWZ(base + 5)] = csub(f1, g5);
        bufA[SWZ(base + 2)] = cadd(f2, g6); bufA[SWZ(base + 6)] = csub(f2, g6);
        bufA[SWZ(base + 3)] = cadd(f3, g7); bufA[SWZ(base + 7)] = csub(f3, g7);
    }
    __syncthreads();

    // ---- inverse DIT passes (stages 4..13) -> natural time order ----
    dit_pass1<8>(bufA, tw, tid);    __syncthreads();
    dit_pass1<32>(bufA, tw, tid);   __syncthreads();
    dit_pass1<128>(bufA, tw, tid);  __syncthreads();
    dit_pass1<512>(bufA, tw, tid);  __syncthreads();
    dit_pass1<2048>(bufA, tw, tid); __syncthreads();

    // ---- output: y = 0.5*(c + n) + D*u, combined across the block pair ----
    const float sc = 0.5f / (float)L;   // 0.5 for (c+n)/2, 1/L for unscaled IFFT
    float* orow = out + (size_t)h * L;
    for (int t = tid; t < L; t += NTH) {
        float2 z = bufA[SWZ(t)];
        float val;
        if (type == 0) {
            val = z.x * sc + Dh * ur[t];
        } else {
            float2 w = twget<false>(tw, t >> 1);      // w[t] = e^{-i pi t/L}
            if (t & 1) w = cmul(w, W16K);
            // n[t] = Re(conj(w[t]) * z) = w.x*z.x + w.y*z.y
            val = (w.x * z.x + w.y * z.y) * sc;
        }
        atomicAdd(&orow[t], val);
    }
}

extern "C" void kernel_launch(void* const* d_in, const int* in_sizes, int n_in,
                              void* d_out, int out_size, void* d_ws, size_t ws_size,
                              hipStream_t stream) {
    (void)in_sizes; (void)n_in; (void)d_ws; (void)ws_size; (void)out_size;
    const float* u        = (const float*)d_in[0];
    const float* Ct_ri    = (const float*)d_in[1];
    const float* B_raw    = (const float*)d_in[2];
    const float* Dp       = (const float*)d_in[3];
    const float* log_step = (const float*)d_in[4];
    const float* Lre      = (const float*)d_in[5];
    const float* Lim      = (const float*)d_in[6];
    const float* p_re     = (const float*)d_in[7];
    const float* p_im     = (const float*)d_in[8];
    const float* q_re     = (const float*)d_in[9];
    const float* q_im     = (const float*)d_in[10];
    const float* Vc_re    = (const float*)d_in[11];
    const float* Vc_im    = (const float*)d_in[12];
    float* out = (float*)d_out;

    // zero the accumulation target (2 atomic addends per element -> deterministic)
    hipMemsetAsync(out, 0, (size_t)H * L * sizeof(float), stream);

    const size_t smem = (size_t)(L + 2048) * sizeof(float2)
                      + 3 * NSTATE * sizeof(float4);
    hipFuncSetAttribute((const void*)s4_split_kernel,
                        hipFuncAttributeMaxDynamicSharedMemorySize, (int)smem);
    s4_split_kernel<<<dim3(2 * H), dim3(NTH), smem, stream>>>(
        u, Ct_ri, B_raw, Dp, log_step, Lre, Lim,
        p_re, p_im, q_re, q_im, Vc_re, Vc_im, out);
}